// Round 1
// baseline (856.924 us; speedup 1.0000x reference)
//
#include <hip/hip_runtime.h>
#include <stdint.h>

#define ROUNDS 64
#define HIDDEN 256
#define BATCH  65536

// ---- workspace layout (u32 units) ----
// m_bits : [ROUNDS][HIDDEN][8] u32 -- bit j of row i = (W[r][i][j] != 0)
// n_bits : [ROUNDS][8] u32        -- bit i = noise[r][i]
// s_bits : [BATCH][8] u32         -- bit i = state[e][i]; updated in place
#define WS_M 0
#define WS_N (ROUNDS * HIDDEN * 8)            // 131072
#define WS_S (WS_N + ROUNDS * 8)              // 131584

#define NM (ROUNDS * HIDDEN * HIDDEN)         // 4194304
#define NN (ROUNDS * HIDDEN)                  // 16384
#define NS (BATCH * HIDDEN)                   // 16777216
#define NTOT (NM + NN + NS)                   // 20987904, /256 = 81984 exact

// Ballot-pack all three f32 inputs into bit arrays. Segment bases are
// multiples of 64 so a wave never straddles segments.
__global__ __launch_bounds__(256) void pack_bits(const float* __restrict__ mat,
                                                 const float* __restrict__ noi,
                                                 const float* __restrict__ sta,
                                                 uint32_t* __restrict__ ws) {
  unsigned g = blockIdx.x * 256u + threadIdx.x;
  float v;
  unsigned long long dstw;  // destination u64 index within ws
  if (g < NM) {
    v = mat[g];
    dstw = (WS_M / 2) + (g >> 6);
  } else if (g < NM + NN) {
    v = noi[g - NM];
    dstw = (WS_N / 2) + ((g - NM) >> 6);
  } else {
    v = sta[g - NM - NN];
    dstw = (WS_S / 2) + ((g - NM - NN) >> 6);
  }
  unsigned long long m = __ballot(v != 0.0f);
  if ((threadIdx.x & 63u) == 0u) ((unsigned long long*)ws)[dstw] = m;
}

// Main hash: 64 elements per block, thread = (quarter q, element e).
// Each thread computes 64 output bits of its element per round.
// Matrix rows are read with wave-uniform addresses -> scalar loads (s_load),
// so the VALU only does and/popcount/insert (~18 ops per output bit).
__global__ __launch_bounds__(256) void hash_main(const uint32_t* __restrict__ mbits,
                                                 const uint32_t* __restrict__ nbits,
                                                 uint32_t* __restrict__ sbits) {
  __shared__ uint32_t st[64][9];  // pad 9: breaks 8-word bank aliasing
  const int t = threadIdx.x;
  const int q = t >> 6;   // quarter (wave id): output bits [q*64, q*64+64)
  const int e = t & 63;   // element within block (lane)
  const int el0 = blockIdx.x * 64;

  // cooperative coalesced load of the block's 64 packed states (2 KB)
  {
    int le = t >> 2, w0 = (t & 3) * 2;
    const uint32_t* p = sbits + (el0 + le) * 8 + w0;
    st[le][w0] = p[0];
    st[le][w0 + 1] = p[1];
  }
  __syncthreads();

  uint32_t s0 = st[e][0], s1 = st[e][1], s2 = st[e][2], s3 = st[e][3],
           s4 = st[e][4], s5 = st[e][5], s6 = st[e][6], s7 = st[e][7];

  const int qq = __builtin_amdgcn_readfirstlane(q);  // force wave-uniformity

  for (int r = 0; r < ROUNDS; ++r) {
    const uint4* rows = (const uint4*)(mbits + (((r << 8) + (qq << 6)) << 3));
    uint32_t nw0 = 0, nw1 = 0;
#pragma unroll 16
    for (int k = 0; k < 32; ++k) {
      uint4 a = rows[2 * k];
      uint4 b = rows[2 * k + 1];
      uint32_t c = __popc(s0 & a.x) + __popc(s1 & a.y) + __popc(s2 & a.z) +
                   __popc(s3 & a.w) + __popc(s4 & b.x) + __popc(s5 & b.y) +
                   __popc(s6 & b.z) + __popc(s7 & b.w);
      nw0 |= (c & 1u) << k;
    }
#pragma unroll 16
    for (int k = 0; k < 32; ++k) {
      uint4 a = rows[64 + 2 * k];
      uint4 b = rows[64 + 2 * k + 1];
      uint32_t c = __popc(s0 & a.x) + __popc(s1 & a.y) + __popc(s2 & a.z) +
                   __popc(s3 & a.w) + __popc(s4 & b.x) + __popc(s5 & b.y) +
                   __popc(s6 & b.z) + __popc(s7 & b.w);
      nw1 |= (c & 1u) << k;
    }
    nw0 ^= nbits[r * 8 + qq * 2];      // uniform -> scalar load
    nw1 ^= nbits[r * 8 + qq * 2 + 1];

    __syncthreads();                   // all quarters done reading old state
    st[e][2 * q] = nw0;
    st[e][2 * q + 1] = nw1;
    __syncthreads();                   // new state visible
    s0 = st[e][0]; s1 = st[e][1]; s2 = st[e][2]; s3 = st[e][3];
    s4 = st[e][4]; s5 = st[e][5]; s6 = st[e][6]; s7 = st[e][7];
  }

  // cooperative coalesced writeback of final packed state
  {
    int le = t >> 2, w0 = (t & 3) * 2;
    uint32_t* p = sbits + (el0 + le) * 8 + w0;
    p[0] = st[le][w0];
    p[1] = st[le][w0 + 1];
  }
}

// Unpack final packed state to f32 output, 4 bits -> float4 per thread.
__global__ __launch_bounds__(256) void unpack_out(const uint32_t* __restrict__ sbits,
                                                  float* __restrict__ out) {
  unsigned g = blockIdx.x * 256u + threadIdx.x;  // one thread per 4 outputs
  unsigned o = g * 4u;
  unsigned el = o >> 8, i = o & 255u;
  uint32_t wv = sbits[el * 8 + (i >> 5)];
  uint32_t b = wv >> (i & 31u);
  float4 f = make_float4((float)(b & 1u), (float)((b >> 1) & 1u),
                         (float)((b >> 2) & 1u), (float)((b >> 3) & 1u));
  *(float4*)(out + o) = f;
}

extern "C" void kernel_launch(void* const* d_in, const int* in_sizes, int n_in,
                              void* d_out, int out_size, void* d_ws, size_t ws_size,
                              hipStream_t stream) {
  const float* sta = (const float*)d_in[0];  // [B, HIDDEN]
  const float* mat = (const float*)d_in[1];  // [ROUNDS, HIDDEN, HIDDEN]
  const float* noi = (const float*)d_in[2];  // [ROUNDS, HIDDEN]
  uint32_t* ws = (uint32_t*)d_ws;            // needs ~2.63 MB

  pack_bits<<<NTOT / 256, 256, 0, stream>>>(mat, noi, sta, ws);
  hash_main<<<BATCH / 64, 256, 0, stream>>>(ws + WS_M, ws + WS_N, ws + WS_S);
  unpack_out<<<NS / 4 / 256, 256, 0, stream>>>(ws + WS_S, (float*)d_out);
}

// Round 2
// 658.671 us; speedup vs baseline: 1.3010x; 1.3010x over previous
//
#include <hip/hip_runtime.h>
#include <stdint.h>

#define ROUNDS 64
#define HIDDEN 256
#define BATCH  65536

#define NM (ROUNDS * HIDDEN * HIDDEN)   // 4194304
#define NN (ROUNDS * HIDDEN)            // 16384
#define NMN (NM + NN)                   // 4210688 ; /256 = 16448 exact

// ws layout (u32 units): m_bits [ROUNDS][HIDDEN][8] then n_bits [ROUNDS][8]
#define WS_N (ROUNDS * HIDDEN * 8)      // 131072

#define LDSS 12  // LDS row stride (u32): 16B-aligned, conflict-free for b128

// Ballot-pack matrices + noise into bit arrays (bit = value != 0).
__global__ __launch_bounds__(256) void pack_mat(const float* __restrict__ mat,
                                                const float* __restrict__ noi,
                                                uint32_t* __restrict__ ws) {
  unsigned g = blockIdx.x * 256u + threadIdx.x;
  float v;
  unsigned long long dstw;
  if (g < NM) {
    v = mat[g];
    dstw = g >> 6;
  } else {
    v = noi[g - NM];
    dstw = (WS_N / 2) + ((g - NM) >> 6);
  }
  unsigned long long m = __ballot(v != 0.0f);
  if ((threadIdx.x & 63u) == 0u) ((unsigned long long*)ws)[dstw] = m;
}

// Fused: pack f32 state -> bits, 64 rounds of GF(2) matvec, unpack -> f32 out.
// Block = 64 elements x 4 quarter-waves. Wave q computes output bits
// [q*64, q*64+64) for all 64 elements (one element per lane).
// parity(sum popc(s_i & r_i)) == popc(xor_i (s_i & r_i)) & 1  -> 15 VALU/bit.
__global__ __launch_bounds__(256, 4) void hash_main(const uint32_t* __restrict__ mbits,
                                                    const uint32_t* __restrict__ nbits,
                                                    const float* __restrict__ sta,
                                                    float* __restrict__ out) {
  __shared__ uint32_t st[2][64 * LDSS];
  const int t = threadIdx.x;
  const int q = __builtin_amdgcn_readfirstlane(t >> 6);  // wave-uniform quarter
  const int e = t & 63;                                  // element lane
  const int el0 = blockIdx.x * 64;

  // ---- pack state: thread t -> element t>>2, u32 word-pair t&3 ----
  {
    int el = t >> 2, wp = t & 3;
    const float4* p = (const float4*)(sta + (size_t)(el0 + el) * 256 + wp * 64);
    uint32_t w0 = 0, w1 = 0;
#pragma unroll
    for (int i = 0; i < 8; ++i) {
      float4 f = p[i];
      uint32_t b = (f.x != 0.f ? 1u : 0u) | (f.y != 0.f ? 2u : 0u) |
                   (f.z != 0.f ? 4u : 0u) | (f.w != 0.f ? 8u : 0u);
      w0 |= b << (i * 4);
    }
#pragma unroll
    for (int i = 0; i < 8; ++i) {
      float4 f = p[8 + i];
      uint32_t b = (f.x != 0.f ? 1u : 0u) | (f.y != 0.f ? 2u : 0u) |
                   (f.z != 0.f ? 4u : 0u) | (f.w != 0.f ? 8u : 0u);
      w1 |= b << (i * 4);
    }
    st[0][el * LDSS + wp * 2] = w0;
    st[0][el * LDSS + wp * 2 + 1] = w1;
  }
  __syncthreads();

  uint4 sa = *(const uint4*)&st[0][e * LDSS];      // bytes e*48+0  (16B aligned)
  uint4 sb = *(const uint4*)&st[0][e * LDSS + 4];  // bytes e*48+16
  uint32_t s0 = sa.x, s1 = sa.y, s2 = sa.z, s3 = sa.w;
  uint32_t s4 = sb.x, s5 = sb.y, s6 = sb.z, s7 = sb.w;

  int cur = 0;
  for (int r = 0; r < ROUNDS; ++r) {
    // wave-uniform row pointer -> scalar (s_load) row fetches
    const uint4* rows = (const uint4*)(mbits + (((r << 8) + (q << 6)) << 3));
    uint32_t nw0 = 0, nw1 = 0;
#pragma unroll
    for (int k = 0; k < 32; ++k) {
      uint4 a = rows[2 * k];
      uint4 b = rows[2 * k + 1];
      uint32_t x = (s0 & a.x) ^ (s1 & a.y) ^ (s2 & a.z) ^ (s3 & a.w) ^
                   (s4 & b.x) ^ (s5 & b.y) ^ (s6 & b.z) ^ (s7 & b.w);
      nw0 |= (uint32_t)(__popc(x) & 1) << k;
    }
#pragma unroll
    for (int k = 0; k < 32; ++k) {
      uint4 a = rows[64 + 2 * k];
      uint4 b = rows[64 + 2 * k + 1];
      uint32_t x = (s0 & a.x) ^ (s1 & a.y) ^ (s2 & a.z) ^ (s3 & a.w) ^
                   (s4 & b.x) ^ (s5 & b.y) ^ (s6 & b.z) ^ (s7 & b.w);
      nw1 |= (uint32_t)(__popc(x) & 1) << k;
    }
    nw0 ^= nbits[r * 8 + q * 2];      // uniform -> scalar load
    nw1 ^= nbits[r * 8 + q * 2 + 1];

    int nxt = cur ^ 1;
    st[nxt][e * LDSS + 2 * q] = nw0;
    st[nxt][e * LDSS + 2 * q + 1] = nw1;
    __syncthreads();                  // single barrier: writes(nxt) -> reads(nxt)
    sa = *(const uint4*)&st[nxt][e * LDSS];
    sb = *(const uint4*)&st[nxt][e * LDSS + 4];
    s0 = sa.x; s1 = sa.y; s2 = sa.z; s3 = sa.w;
    s4 = sb.x; s5 = sb.y; s6 = sb.z; s7 = sb.w;
    cur = nxt;
  }

  // ---- unpack to f32: final state sits in st[cur] (ordered by last barrier) ----
#pragma unroll
  for (int i = 0; i < 16; ++i) {
    unsigned f = (unsigned)t * 4u + (unsigned)i * 1024u;  // flat idx in block's out tile
    unsigned el = f >> 8, j = f & 255u;
    uint32_t w = st[cur][el * LDSS + (j >> 5)];
    uint32_t b = w >> (j & 31u);
    float4 o = make_float4((float)(b & 1u), (float)((b >> 1) & 1u),
                           (float)((b >> 2) & 1u), (float)((b >> 3) & 1u));
    *(float4*)(out + (size_t)el0 * 256 + f) = o;
  }
}

extern "C" void kernel_launch(void* const* d_in, const int* in_sizes, int n_in,
                              void* d_out, int out_size, void* d_ws, size_t ws_size,
                              hipStream_t stream) {
  const float* sta = (const float*)d_in[0];  // [B, HIDDEN]
  const float* mat = (const float*)d_in[1];  // [ROUNDS, HIDDEN, HIDDEN]
  const float* noi = (const float*)d_in[2];  // [ROUNDS, HIDDEN]
  uint32_t* ws = (uint32_t*)d_ws;            // needs ~514 KB

  pack_mat<<<NMN / 256, 256, 0, stream>>>(mat, noi, ws);
  hash_main<<<BATCH / 64, 256, 0, stream>>>(ws, ws + WS_N, sta, (float*)d_out);
}

// Round 3
// 488.620 us; speedup vs baseline: 1.7538x; 1.3480x over previous
//
#include <hip/hip_runtime.h>
#include <stdint.h>

#define ROUNDS 64
#define HIDDEN 256
#define BATCH  65536

typedef int v4i  __attribute__((ext_vector_type(4)));
typedef int v16i __attribute__((ext_vector_type(16)));

// ws layout: W_i8 [64][256][256] (4 MB), then noise bit-words u32 [64][8] (2 KB)
#define WS_NB (ROUNDS * HIDDEN * HIDDEN)   // byte offset of noise bits

// ---- pack W: f32 {-1,0,1} -> i8, one thread per 4 values ----
__global__ __launch_bounds__(256) void pack_w(const float* __restrict__ mat,
                                              uint32_t* __restrict__ w32) {
  unsigned g = blockIdx.x * 256u + threadIdx.x;  // g < 64*256*64
  float4 f = ((const float4*)mat)[g];
  uint32_t b = ((uint32_t)(int)f.x & 255u) | (((uint32_t)(int)f.y & 255u) << 8) |
               (((uint32_t)(int)f.z & 255u) << 16) | (((uint32_t)(int)f.w & 255u) << 24);
  w32[g] = b;
}

// ---- pack noise bits: ballot, 64 bits -> u64 ----
__global__ __launch_bounds__(256) void pack_n(const float* __restrict__ noi,
                                              unsigned long long* __restrict__ nb64) {
  unsigned g = blockIdx.x * 256u + threadIdx.x;  // g < 16384
  unsigned long long m = __ballot(noi[g] != 0.0f);
  if ((threadIdx.x & 63u) == 0u) nb64[g >> 6] = m;
}

// ---- main: per block 256 elements through all 64 rounds via i8 MFMA ----
// State T in LDS as i8 bytes, layout [kb=k/16][el][16] (64 KB).
// Round: C^T = W * S^T  (M=256 bits, N=256 el, K=256), C/D reg quads =
// 4 consecutive output bits at fixed el -> pack u32 -> ds_write_b32 back
// into the same [kb][el][16] layout (k-contiguous, as A/B frags need).
__global__ __launch_bounds__(512, 2) void hash_mfma(const uint8_t* __restrict__ W,
                                                    const uint32_t* __restrict__ NB,
                                                    const float* __restrict__ sta,
                                                    float* __restrict__ out) {
  __shared__ uint8_t T[16 * 4096];  // [kb][el][16]
  const int t = threadIdx.x;
  const int lane = t & 63;
  const int wv = t >> 6;            // 0..7
  const int m0 = (wv & 3) * 64;     // bit-slice
  const int n0 = (wv >> 2) * 128;   // element-slice
  const int l31 = lane & 31;
  const int lh = lane >> 5;         // k-half within fragment
  const int el0 = blockIdx.x * 256;

  // ---- init: f32 state -> bytes in T ----
  {
    int el = t >> 1, h = t & 1;
    const float4* sp = (const float4*)(sta + (size_t)(el0 + el) * 256 + h * 128);
#pragma unroll
    for (int g = 0; g < 8; ++g) {
      uint32_t w[4];
#pragma unroll
      for (int wi = 0; wi < 4; ++wi) {
        float4 f = sp[g * 4 + wi];
        w[wi] = ((__builtin_bit_cast(uint32_t, f.x) >> 23) & 1u) |
                (((__builtin_bit_cast(uint32_t, f.y) >> 23) & 1u) << 8) |
                (((__builtin_bit_cast(uint32_t, f.z) >> 23) & 1u) << 16) |
                (((__builtin_bit_cast(uint32_t, f.w) >> 23) & 1u) << 24);
      }
      *(uint4*)&T[(h * 8 + g) * 4096 + el * 16] = make_uint4(w[0], w[1], w[2], w[3]);
    }
  }
  __syncthreads();

  for (int r = 0; r < ROUNDS; ++r) {
    const uint8_t* Wr = W + (size_t)r * 65536;
    uint2 nw = *(const uint2*)(NB + r * 8 + (m0 >> 5));  // noise bits, rows [m0,m0+64)
    v16i acc[2][4] = {};
#pragma unroll
    for (int ks = 0; ks < 8; ++ks) {
      v4i a[2], b[4];
#pragma unroll
      for (int tm = 0; tm < 2; ++tm)  // A = W rows (bits), global/L2 direct
        a[tm] = *(const v4i*)(Wr + (size_t)(m0 + tm * 32 + l31) * 256 + ks * 32 + lh * 16);
      int kb = ks * 2 + lh;
#pragma unroll
      for (int tn = 0; tn < 4; ++tn)  // B = S^T from LDS
        b[tn] = *(const v4i*)&T[kb * 4096 + (n0 + tn * 32 + l31) * 16];
#pragma unroll
      for (int tm = 0; tm < 2; ++tm)
#pragma unroll
        for (int tn = 0; tn < 4; ++tn)
          acc[tm][tn] = __builtin_amdgcn_mfma_i32_32x32x32_i8(a[tm], b[tn], acc[tm][tn], 0, 0, 0);
    }
    __syncthreads();  // all reads of T complete

    // epilogue: bit = (c & 1) ^ noise, packed 4 bits (consecutive k') per u32
#pragma unroll
    for (int tm = 0; tm < 2; ++tm) {
      uint32_t nv = (tm ? nw.y : nw.x) >> (lh * 4);
#pragma unroll
      for (int q = 0; q < 4; ++q) {
        uint32_t nib = (nv >> (q * 8)) & 15u;
        uint32_t nx = (nib & 1u) | ((nib & 2u) << 7) | ((nib & 4u) << 14) | ((nib & 8u) << 21);
        int k0 = m0 + tm * 32 + q * 8 + lh * 4;  // first of 4 consecutive output bits
#pragma unroll
        for (int tn = 0; tn < 4; ++tn) {
          v16i c = acc[tm][tn];
          uint32_t pk = (uint32_t)(c[q * 4 + 0] & 1) | ((uint32_t)(c[q * 4 + 1] & 1) << 8) |
                        ((uint32_t)(c[q * 4 + 2] & 1) << 16) | ((uint32_t)(c[q * 4 + 3] & 1) << 24);
          pk ^= nx;
          *(uint32_t*)&T[(k0 >> 4) * 4096 + (n0 + tn * 32 + l31) * 16 + (k0 & 15)] = pk;
        }
      }
    }
    __syncthreads();  // new state visible
  }

  // ---- final: T bytes -> f32 out ----
  {
    int el = t >> 1, h = t & 1;
    float4* op = (float4*)(out + (size_t)(el0 + el) * 256 + h * 128);
#pragma unroll
    for (int g = 0; g < 8; ++g) {
      uint4 w = *(const uint4*)&T[(h * 8 + g) * 4096 + el * 16];
      uint32_t ws_[4] = {w.x, w.y, w.z, w.w};
#pragma unroll
      for (int wi = 0; wi < 4; ++wi) {
        uint32_t u = ws_[wi];
        op[g * 4 + wi] = make_float4((float)(u & 255u), (float)((u >> 8) & 255u),
                                     (float)((u >> 16) & 255u), (float)((u >> 24) & 255u));
      }
    }
  }
}

extern "C" void kernel_launch(void* const* d_in, const int* in_sizes, int n_in,
                              void* d_out, int out_size, void* d_ws, size_t ws_size,
                              hipStream_t stream) {
  const float* sta = (const float*)d_in[0];  // [B, HIDDEN]
  const float* mat = (const float*)d_in[1];  // [ROUNDS, HIDDEN, HIDDEN]
  const float* noi = (const float*)d_in[2];  // [ROUNDS, HIDDEN]
  uint8_t* wsb = (uint8_t*)d_ws;             // needs ~4.2 MB

  pack_w<<<(ROUNDS * HIDDEN * HIDDEN / 4) / 256, 256, 0, stream>>>(mat, (uint32_t*)wsb);
  pack_n<<<(ROUNDS * HIDDEN) / 256, 256, 0, stream>>>(noi, (unsigned long long*)(wsb + WS_NB));
  hash_mfma<<<BATCH / 256, 512, 0, stream>>>(wsb, (const uint32_t*)(wsb + WS_NB), sta,
                                             (float*)d_out);
}

// Round 4
// 313.518 us; speedup vs baseline: 2.7333x; 1.5585x over previous
//
#include <hip/hip_runtime.h>
#include <stdint.h>

#define ROUNDS 64
#define HIDDEN 256
#define BATCH  65536

typedef int   v4i  __attribute__((ext_vector_type(4)));
typedef int   v8i  __attribute__((ext_vector_type(8)));
typedef float v16f __attribute__((ext_vector_type(16)));

// ws layout: Wpk fp4 fragments [r][mt=8][ks=4][lane=64][16B] = 2 MB,
// then noise masks u32 [r][KB=8][lhw=2][g=2] = 8 KB.
#define WPK_BYTES (ROUNDS * 8 * 4 * 64 * 16)

// sigma: nibble slot n (0..31) within a 32-k chunk holds logical k-offset rho(n).
// Chosen so MFMA C-layout rows (j&3)+8*(j>>2)+4*lh for lane-half lh are the
// contiguous nibbles lh*16+j  ->  epilogue = 1 conflict-free ds_write_b64/lane.
// Applied identically to W-pack, state init, epilogue, and final unpack, so it
// cancels inside the MFMA dot product.
__host__ __device__ constexpr int rho(int n) {
  return 4 * (n >> 4) + (n & 3) + 8 * ((n >> 2) & 3);
}

// ---- pack W into fp4 A-fragments, sigma-permuted, coalesced-load layout ----
// thread = (r, row, kwin);  kwin = ks*2+lh selects a 32-column window.
__global__ __launch_bounds__(256) void pack_w4(const float* __restrict__ mat,
                                               uint32_t* __restrict__ wpk) {
  unsigned tg = blockIdx.x * 256u + threadIdx.x;  // (r*256+row)*8 + kwin
  unsigned kwin = tg & 7u;
  unsigned rr = tg >> 3;                          // r*256 + row
  const float4* F4 = (const float4*)(mat + (size_t)rr * 256 + kwin * 32);
  float4 F[8];
#pragma unroll
  for (int i = 0; i < 8; ++i) F[i] = F4[i];
  const float* Ff = (const float*)F;
  uint32_t w[4] = {0, 0, 0, 0};
#pragma unroll
  for (int n = 0; n < 32; ++n) {
    uint32_t u = __builtin_bit_cast(uint32_t, Ff[rho(n)]);
    // fp4 e2m1: 0 -> 0b0000, +1 -> 0b0010, -1 -> 0b1010
    uint32_t nib = ((u & 0x7fffffffu) ? 2u : 0u) | ((u >> 28) & 8u);
    w[n >> 3] |= nib << ((n & 7) * 4);
  }
  unsigned r = rr >> 8, row = rr & 255u;
  unsigned mt = row >> 5, lh = kwin & 1u, ks = kwin >> 1;
  unsigned lane = lh * 32u + (row & 31u);
  *(uint4*)(wpk + ((((r * 8u + mt) * 4u + ks) * 64u + lane) << 2)) =
      make_uint4(w[0], w[1], w[2], w[3]);
}

// ---- noise masks in packed-nibble space: bit(4*nb+1) of word (KB,lhw,g) ----
__global__ __launch_bounds__(256) void pack_nm(const float* __restrict__ noi,
                                               uint32_t* __restrict__ nmask) {
  unsigned tg = blockIdx.x * 256u + threadIdx.x;  // < 2048
  unsigned g = tg & 1u, lhw = (tg >> 1) & 1u, KB = (tg >> 2) & 7u, r = tg >> 5;
  const float* np = noi + r * 256 + KB * 32 + 4 * lhw;
  uint32_t m = 0;
#pragma unroll
  for (int nb = 0; nb < 8; ++nb) {
    int row = (nb & 3) + 8 * (2 * (int)g + (nb >> 2));
    if (np[row] != 0.0f) m |= 1u << (4 * nb + 1);
  }
  nmask[tg] = m;
}

// ---- main: 128 elements/block, 8 waves; wave wv = output rows [wv*32, wv*32+32)
// for all 128 elements. fp4 MFMA 32x32x64, K=256 in 4 steps. State double-
// buffered in LDS as [buf][KB=8][el=128][16B chunks], sigma-nibble order.
__global__ __launch_bounds__(512, 4) void hash4(const uint32_t* __restrict__ wpk,
                                                const uint32_t* __restrict__ nmask,
                                                const float* __restrict__ sta,
                                                float* __restrict__ out) {
  __shared__ uint8_t T[2][8][128][16];  // 32 KB
  const int t = threadIdx.x;
  const int wv = __builtin_amdgcn_readfirstlane(t >> 6);  // m-tile 0..7
  const int lane = t & 63;
  const int l31 = lane & 31;
  const int lh = lane >> 5;
  const int el0 = blockIdx.x * 128;

  // ---- initial pack: f32 -> sigma-ordered fp4 nibbles (4 logical k per u16) ----
#pragma unroll
  for (int i = 0; i < 16; ++i) {
    unsigned flat = (unsigned)i * 512u + t;  // float4 idx in 128x256 slab
    unsigned el = flat >> 6, k4 = flat & 63u;
    float4 f = ((const float4*)(sta + (size_t)el0 * 256))[flat];
    uint32_t v = ((f.x != 0.f) ? 0x2u : 0u) | ((f.y != 0.f) ? 0x20u : 0u) |
                 ((f.z != 0.f) ? 0x200u : 0u) | ((f.w != 0.f) ? 0x2000u : 0u);
    unsigned KB = k4 >> 3, k4c = k4 & 7u;
    unsigned byteoff = (k4c & 1u) * 8u + 2u * (k4c >> 1);  // sigma^-1 of 4 rows
    *(uint16_t*)&T[0][KB][el][byteoff] = (uint16_t)v;
  }
  __syncthreads();

  for (int r = 0; r < ROUNDS; ++r) {
    const int rb = r & 1, nx = rb ^ 1;
    const uint32_t* nmr = nmask + ((r * 8 + wv) << 2);  // wave-uniform -> s_load
    uint32_t nm0 = lh ? nmr[2] : nmr[0];
    uint32_t nm1 = lh ? nmr[3] : nmr[1];
    const uint32_t* wbase = wpk + (((r * 8 + wv) * 4) << 8);

    v16f acc[4] = {};
#pragma unroll
    for (int ks = 0; ks < 4; ++ks) {
      v4i a4 = *(const v4i*)(wbase + ks * 256 + lane * 4);  // coalesced 1KB/wave
      v8i A8 = {a4.x, a4.y, a4.z, a4.w, 0, 0, 0, 0};        // fp4 uses regs 0-3
      const int kb = 2 * ks + lh;
#pragma unroll
      for (int tn = 0; tn < 4; ++tn) {
        v4i b4 = *(const v4i*)&T[rb][kb][tn * 32 + l31][0];  // conflict-free b128
        v8i B8 = {b4.x, b4.y, b4.z, b4.w, 0, 0, 0, 0};
        acc[tn] = __builtin_amdgcn_mfma_scale_f32_32x32x64_f8f6f4(
            A8, B8, acc[tn], 4, 4, 0, 127, 0, 127);  // fmt=fp4, scale=2^0
      }
    }

    // epilogue: bit = ((int)c & 1) ^ noise; lane's 16 rows are its own 8 bytes
#pragma unroll
    for (int tn = 0; tn < 4; ++tn) {
      uint32_t lo = 0, hi = 0;
#pragma unroll
      for (int j = 0; j < 8; ++j)
        lo |= (((uint32_t)(int)acc[tn][j]) & 1u) << (4 * j + 1);
#pragma unroll
      for (int j = 0; j < 8; ++j)
        hi |= (((uint32_t)(int)acc[tn][8 + j]) & 1u) << (4 * j + 1);
      lo ^= nm0;
      hi ^= nm1;
      *(uint2*)&T[nx][wv][tn * 32 + l31][lh * 8] = make_uint2(lo, hi);
    }
    __syncthreads();  // single barrier/round (double-buffered)
  }

  // ---- final unpack: buf 0 holds the round-63 output ----
#pragma unroll
  for (int i = 0; i < 16; ++i) {
    unsigned flat = (unsigned)i * 512u + t;
    unsigned el = flat >> 6, k4 = flat & 63u;
    unsigned KB = k4 >> 3, k4c = k4 & 7u;
    unsigned byteoff = (k4c & 1u) * 8u + 2u * (k4c >> 1);
    uint32_t v = *(const uint16_t*)&T[0][KB][el][byteoff];
    float4 o = make_float4((float)((v >> 1) & 1u), (float)((v >> 5) & 1u),
                           (float)((v >> 9) & 1u), (float)((v >> 13) & 1u));
    ((float4*)(out + (size_t)el0 * 256))[flat] = o;
  }
}

extern "C" void kernel_launch(void* const* d_in, const int* in_sizes, int n_in,
                              void* d_out, int out_size, void* d_ws, size_t ws_size,
                              hipStream_t stream) {
  const float* sta = (const float*)d_in[0];  // [B, HIDDEN]
  const float* mat = (const float*)d_in[1];  // [ROUNDS, HIDDEN, HIDDEN]
  const float* noi = (const float*)d_in[2];  // [ROUNDS, HIDDEN]
  uint8_t* wsb = (uint8_t*)d_ws;             // needs ~2.01 MB

  pack_w4<<<512, 256, 0, stream>>>(mat, (uint32_t*)wsb);
  pack_nm<<<8, 256, 0, stream>>>(noi, (uint32_t*)(wsb + WPK_BYTES));
  hash4<<<512, 512, 0, stream>>>((const uint32_t*)wsb,
                                 (const uint32_t*)(wsb + WPK_BYTES), sta,
                                 (float*)d_out);
}

// Round 6
// 299.336 us; speedup vs baseline: 2.8627x; 1.0474x over previous
//
#include <hip/hip_runtime.h>
#include <stdint.h>

#define ROUNDS 64
#define HIDDEN 256
#define BATCH  65536

typedef int   v4i  __attribute__((ext_vector_type(4)));
typedef int   v8i  __attribute__((ext_vector_type(8)));
typedef float v16f __attribute__((ext_vector_type(16)));

// ws layout: Wpk fp4 fragments [r][mt=8][ks=4][lane=64][16B] = 2 MB,
// then noise floats [r][wv=8][lh=2][j=16] f32 = 64 KB.
#define WPK_BYTES (ROUNDS * 8 * 4 * 64 * 16)

// sigma: nibble slot n (0..31) within a 32-k chunk holds logical k-offset
// rho(n). Rows (j&3)+8*(j>>2)+4*lh of the 32x32 C layout land in each lane's
// own contiguous 8 bytes -> 1 conflict-free ds_write_b64 epilogue. Applied
// identically to W-pack, state init, and unpack, so it cancels in the dot.
__host__ __device__ constexpr int rho(int n) {
  return 4 * (n >> 4) + (n & 3) + 8 * ((n >> 2) & 3);
}

// ---- pack W into fp4 A-fragments (blocks 0..511) and noise->f32 in
// C-layout row order (blocks 512..575) ----
__global__ __launch_bounds__(256) void pack_w4(const float* __restrict__ mat,
                                               const float* __restrict__ noi,
                                               uint32_t* __restrict__ wpk,
                                               float* __restrict__ nf) {
  if (blockIdx.x >= 512) {  // noise: nf[r][wv][lh][j] = noise[r][row(j,lh)+wv*32]
    unsigned tg = (blockIdx.x - 512) * 256u + threadIdx.x;  // < 16384
    unsigned j = tg & 15u, lh = (tg >> 4) & 1u, wv = (tg >> 5) & 7u, r = tg >> 8;
    unsigned row = wv * 32u + (j & 3u) + 8u * (j >> 2) + 4u * lh;
    nf[tg] = noi[r * 256u + row];
    return;
  }
  unsigned tg = blockIdx.x * 256u + threadIdx.x;  // (r*256+row)*8 + kwin
  unsigned kwin = tg & 7u;
  unsigned rr = tg >> 3;  // r*256 + row
  const float4* F4 = (const float4*)(mat + (size_t)rr * 256 + kwin * 32);
  float4 F[8];
#pragma unroll
  for (int i = 0; i < 8; ++i) F[i] = F4[i];
  const float* Ff = (const float*)F;
  uint32_t w[4] = {0, 0, 0, 0};
#pragma unroll
  for (int n = 0; n < 32; ++n) {
    uint32_t u = __builtin_bit_cast(uint32_t, Ff[rho(n)]);
    // fp4 e2m1: 0 -> 0b0000, +1 -> 0b0010, -1 -> 0b1010
    uint32_t nib = ((u & 0x7fffffffu) ? 2u : 0u) | ((u >> 28) & 8u);
    w[n >> 3] |= nib << ((n & 7) * 4);
  }
  unsigned r = rr >> 8, row = rr & 255u;
  unsigned mt = row >> 5, lh = kwin & 1u, ks = kwin >> 1;
  unsigned lane = lh * 32u + (row & 31u);
  *(uint4*)(wpk + ((((r * 8u + mt) * 4u + ks) * 64u + lane) << 2)) =
      make_uint4(w[0], w[1], w[2], w[3]);
}

// ---- main: 128 el/block, 8 waves; wave wv = rows [wv*32, wv*32+32) for all
// 128 elements. fp4 MFMA 32x32x64, K=256 in 4 steps, noise as MFMA C-init,
// bias-trick epilogue. State double-buffered in LDS [buf][KB=8][el=128][16B].
// NOTE: barrier is __syncthreads() — the raw lgkm-only s_barrier variant
// produced warm-state-dependent divergence (round-5 FAILED experiment).
__global__ __launch_bounds__(512, 4) void hash4(const uint32_t* __restrict__ wpk,
                                                const float* __restrict__ nf,
                                                const float* __restrict__ sta,
                                                float* __restrict__ out) {
  __shared__ uint8_t T[2][8][128][16];  // 32 KB
  const int t = threadIdx.x;
  const int wv = __builtin_amdgcn_readfirstlane(t >> 6);  // m-tile 0..7
  const int lane = t & 63;
  const int l31 = lane & 31;
  const int lh = lane >> 5;
  const int el0 = blockIdx.x * 128;

  // ---- initial pack: f32 -> sigma-ordered fp4 nibbles (4 logical k per u16) ----
#pragma unroll
  for (int i = 0; i < 16; ++i) {
    unsigned flat = (unsigned)i * 512u + t;  // float4 idx in 128x256 slab
    unsigned el = flat >> 6, k4 = flat & 63u;
    float4 f = ((const float4*)(sta + (size_t)el0 * 256))[flat];
    uint32_t v = ((f.x != 0.f) ? 0x2u : 0u) | ((f.y != 0.f) ? 0x20u : 0u) |
                 ((f.z != 0.f) ? 0x200u : 0u) | ((f.w != 0.f) ? 0x2000u : 0u);
    unsigned KB = k4 >> 3, k4c = k4 & 7u;
    unsigned byteoff = (k4c & 1u) * 8u + 2u * (k4c >> 1);  // sigma^-1 of 4 rows
    *(uint16_t*)&T[0][KB][el][byteoff] = (uint16_t)v;
  }
  __syncthreads();

  const v4i zero4 = {0, 0, 0, 0};
  // prefetch round-0 A fragments + noise C-init
  v4i ap[4];
  {
    const uint32_t* wb = wpk + ((wv * 4) << 8);
#pragma unroll
    for (int ks = 0; ks < 4; ++ks) ap[ks] = *(const v4i*)(wb + ks * 256 + lane * 4);
  }
  v16f NZ = *(const v16f*)(nf + (wv * 2 + lh) * 16);

  for (int r = 0; r < ROUNDS; ++r) {
    const int rb = r & 1, nx = rb ^ 1;
    v16f acc[4];
#pragma unroll
    for (int ks = 0; ks < 4; ++ks) {
      v8i A8 = __builtin_shufflevector(ap[ks], zero4, 0, 1, 2, 3, 4, 5, 6, 7);
      const int kb = 2 * ks + lh;
#pragma unroll
      for (int tn = 0; tn < 4; ++tn) {
        v4i b4 = *(const v4i*)&T[rb][kb][tn * 32 + l31][0];  // conflict-free b128
        v8i B8 = __builtin_shufflevector(b4, zero4, 0, 1, 2, 3, 4, 5, 6, 7);
        acc[tn] = __builtin_amdgcn_mfma_scale_f32_32x32x64_f8f6f4(
            A8, B8, (ks == 0) ? NZ : acc[tn], 4, 4, 0, 127, 0, 127);
      }
    }

    // prefetch next round's A + noise (r=63 wraps to 0 -> no OOB, dead value)
    {
      const int rn = (r + 1) & 63;
      const uint32_t* wb = wpk + (((rn * 8 + wv) * 4) << 8);
#pragma unroll
      for (int ks = 0; ks < 4; ++ks) ap[ks] = *(const v4i*)(wb + ks * 256 + lane * 4);
      NZ = *(const v16f*)(nf + ((rn * 8 + wv) * 2 + lh) * 16);
    }

    // epilogue: bias trick puts integer LSB at bit 1 == fp4 "+1" nibble bit.
    // (acc+noise) in [-256,257]; +1.5*2^22 stays in [2^22,2^23): exact, ulp=0.5.
#pragma unroll
    for (int tn = 0; tn < 4; ++tn) {
      uint32_t lo = 0, hi = 0;
#pragma unroll
      for (int j = 7; j >= 0; --j)
        lo = (lo << 4) | (__builtin_bit_cast(uint32_t, acc[tn][j] + 6291456.0f) & 2u);
#pragma unroll
      for (int j = 15; j >= 8; --j)
        hi = (hi << 4) | (__builtin_bit_cast(uint32_t, acc[tn][j] + 6291456.0f) & 2u);
      *(uint2*)&T[nx][wv][tn * 32 + l31][lh * 8] = make_uint2(lo, hi);
    }

    __syncthreads();  // single barrier/round (double-buffered state)
  }

  // ---- final unpack: buf 0 holds the round-63 output ----
#pragma unroll
  for (int i = 0; i < 16; ++i) {
    unsigned flat = (unsigned)i * 512u + t;
    unsigned el = flat >> 6, k4 = flat & 63u;
    unsigned KB = k4 >> 3, k4c = k4 & 7u;
    unsigned byteoff = (k4c & 1u) * 8u + 2u * (k4c >> 1);
    uint32_t v = *(const uint16_t*)&T[0][KB][el][byteoff];
    float4 o = make_float4((float)((v >> 1) & 1u), (float)((v >> 5) & 1u),
                           (float)((v >> 9) & 1u), (float)((v >> 13) & 1u));
    ((float4*)(out + (size_t)el0 * 256))[flat] = o;
  }
}

extern "C" void kernel_launch(void* const* d_in, const int* in_sizes, int n_in,
                              void* d_out, int out_size, void* d_ws, size_t ws_size,
                              hipStream_t stream) {
  const float* sta = (const float*)d_in[0];  // [B, HIDDEN]
  const float* mat = (const float*)d_in[1];  // [ROUNDS, HIDDEN, HIDDEN]
  const float* noi = (const float*)d_in[2];  // [ROUNDS, HIDDEN]
  uint8_t* wsb = (uint8_t*)d_ws;             // needs ~2.07 MB

  pack_w4<<<576, 256, 0, stream>>>(mat, noi, (uint32_t*)wsb,
                                   (float*)(wsb + WPK_BYTES));
  hash4<<<512, 512, 0, stream>>>((const uint32_t*)wsb,
                                 (const float*)(wsb + WPK_BYTES), sta,
                                 (float*)d_out);
}